// Round 1
// baseline (3997.641 us; speedup 1.0000x reference)
//
#include <hip/hip_runtime.h>

#define B_   256
#define T_   10
#define BT   2560
#define NSP  49
#define VD   512
#define AD   128
#define HD   256
#define QD   128
#define BETA 0.5f

// ---------------- audio transpose: [T,B,AD] -> [B,T,AD] (also = audio_feature) ----
__global__ __launch_bounds__(128) void k_audio(const float* __restrict__ audio,
                                               float* __restrict__ out2) {
  int bt = blockIdx.x;
  int b = bt / T_, t = bt - b * T_;
  out2[(size_t)bt * AD + threadIdx.x] = audio[((size_t)t * B_ + b) * AD + threadIdx.x];
}

// ---------------- generic fp32 GEMM: C = act(alpha*(A @ W^T) + bias) --------------
// A [M,K] row-major, W [N,K] row-major, C [M,N]. M%128==0, N%128==0, K%8==0.
// ACT: 0 none, 1 relu, 2 sigmoid. 128x128 tile, BK=8, 256 threads, 8x8 per thread.
template <int ACT>
__global__ __launch_bounds__(256) void k_gemm(const float* __restrict__ A,
                                              const float* __restrict__ W,
                                              const float* __restrict__ bias,
                                              float* __restrict__ C,
                                              int M, int N, int K, float alpha) {
  __shared__ __align__(16) float As[8][132];
  __shared__ __align__(16) float Ws[8][132];
  const int t = threadIdx.x;
  const int tx = t & 15, ty = t >> 4;
  const int rowBase = blockIdx.y * 128;
  const int colBase = blockIdx.x * 128;
  const int lrow = t >> 1, lq = t & 1;
  const float* Ap = A + (size_t)(rowBase + lrow) * K + lq * 4;
  const float* Wp = W + (size_t)(colBase + lrow) * K + lq * 4;
  float acc[8][8] = {};
  for (int k0 = 0; k0 < K; k0 += 8) {
    const float4 av = *(const float4*)(Ap + k0);
    const float4 wv = *(const float4*)(Wp + k0);
    __syncthreads();
    As[lq * 4 + 0][lrow] = av.x; As[lq * 4 + 1][lrow] = av.y;
    As[lq * 4 + 2][lrow] = av.z; As[lq * 4 + 3][lrow] = av.w;
    Ws[lq * 4 + 0][lrow] = wv.x; Ws[lq * 4 + 1][lrow] = wv.y;
    Ws[lq * 4 + 2][lrow] = wv.z; Ws[lq * 4 + 3][lrow] = wv.w;
    __syncthreads();
#pragma unroll
    for (int kk = 0; kk < 8; ++kk) {
      const float4 a0 = *(const float4*)&As[kk][ty * 8];
      const float4 a1 = *(const float4*)&As[kk][ty * 8 + 4];
      const float4 w0 = *(const float4*)&Ws[kk][tx * 8];
      const float4 w1 = *(const float4*)&Ws[kk][tx * 8 + 4];
      const float a_[8] = {a0.x, a0.y, a0.z, a0.w, a1.x, a1.y, a1.z, a1.w};
      const float w_[8] = {w0.x, w0.y, w0.z, w0.w, w1.x, w1.y, w1.z, w1.w};
#pragma unroll
      for (int i = 0; i < 8; ++i)
#pragma unroll
        for (int j = 0; j < 8; ++j)
          acc[i][j] = fmaf(a_[i], w_[j], acc[i][j]);
    }
  }
  const float4 b0 = *(const float4*)(bias + colBase + tx * 8);
  const float4 b1 = *(const float4*)(bias + colBase + tx * 8 + 4);
  const float bb[8] = {b0.x, b0.y, b0.z, b0.w, b1.x, b1.y, b1.z, b1.w};
#pragma unroll
  for (int i = 0; i < 8; ++i) {
    float* crow = C + (size_t)(rowBase + ty * 8 + i) * N + colBase + tx * 8;
    float o[8];
#pragma unroll
    for (int j = 0; j < 8; ++j) {
      float x = acc[i][j] * alpha + bb[j];
      if (ACT == 1) x = fmaxf(x, 0.f);
      if (ACT == 2) x = 1.f / (1.f + __expf(-x));
      o[j] = x;
    }
    *(float4*)(crow)     = make_float4(o[0], o[1], o[2], o[3]);
    *(float4*)(crow + 4) = make_float4(o[4], o[5], o[6], o[7]);
  }
}

// ---------------- per-bt attention: softmax(qk^T)@v + residual + LN + row-sum -----
__global__ __launch_bounds__(512) void k_attn(const float* __restrict__ q,
                                              const float* __restrict__ k,
                                              const float* __restrict__ v,
                                              const float* __restrict__ vf,
                                              const float* __restrict__ ln_g,
                                              const float* __restrict__ ln_b,
                                              float* __restrict__ vf2,
                                              float* __restrict__ vsum) {
  const int bt = blockIdx.x;
  const int t = threadIdx.x;
  __shared__ float qs[NSP][129];
  __shared__ float ks[NSP][129];
  __shared__ float at[NSP][50];
  __shared__ float red[2][NSP][8];
  __shared__ float mu_s[NSP], rs_s[NSP];

  const float* qg = q + (size_t)bt * NSP * QD;
  const float* kg = k + (size_t)bt * NSP * QD;
  for (int i = t; i < NSP * QD; i += 512) {
    int n = i >> 7, c = i & (QD - 1);
    qs[n][c] = qg[i];
    ks[n][c] = kg[i];
  }
  __syncthreads();
  for (int p = t; p < NSP * NSP; p += 512) {
    int n = p / NSP, m = p - n * NSP;
    float s = 0.f;
#pragma unroll 16
    for (int j = 0; j < QD; ++j) s = fmaf(qs[n][j], ks[m][j], s);
    at[n][m] = s;
  }
  __syncthreads();
  if (t < NSP) {
    float mx = -1e30f;
    for (int m2 = 0; m2 < NSP; ++m2) mx = fmaxf(mx, at[t][m2]);
    float sum = 0.f;
    for (int m2 = 0; m2 < NSP; ++m2) { float e = __expf(at[t][m2] - mx); at[t][m2] = e; sum += e; }
    float inv = 1.f / sum;
    for (int m2 = 0; m2 < NSP; ++m2) at[t][m2] *= inv;
  }
  __syncthreads();
  const int d = t;  // 0..511
  const float* vg  = v  + (size_t)bt * NSP * VD + d;
  const float* vfg = vf + (size_t)bt * NSP * VD + d;
  float xv[NSP] = {};
  for (int m2 = 0; m2 < NSP; ++m2) {
    const float vm = vg[(size_t)m2 * VD];
#pragma unroll
    for (int n = 0; n < NSP; ++n) xv[n] = fmaf(at[n][m2], vm, xv[n]);
  }
#pragma unroll
  for (int n = 0; n < NSP; ++n) xv[n] += vfg[(size_t)n * VD];
  const int lane = t & 63, wid = t >> 6;
#pragma unroll
  for (int n = 0; n < NSP; ++n) {
    float s1 = xv[n], s2 = xv[n] * xv[n];
    for (int off = 32; off; off >>= 1) { s1 += __shfl_down(s1, off); s2 += __shfl_down(s2, off); }
    if (lane == 0) { red[0][n][wid] = s1; red[1][n][wid] = s2; }
  }
  __syncthreads();
  if (t < NSP) {
    float s1 = 0.f, s2 = 0.f;
    for (int w2 = 0; w2 < 8; ++w2) { s1 += red[0][t][w2]; s2 += red[1][t][w2]; }
    const float mu = s1 * (1.f / VD);
    const float var = s2 * (1.f / VD) - mu * mu;
    mu_s[t] = mu;
    rs_s[t] = rsqrtf(var + 1e-5f);
  }
  __syncthreads();
  const float gd = ln_g[d], bd = ln_b[d];
  float* o = vf2 + (size_t)bt * NSP * VD + d;
  float vs = 0.f;
#pragma unroll
  for (int n = 0; n < NSP; ++n) {
    const float y = (xv[n] - mu_s[n]) * rs_s[n] * gd + bd;
    o[(size_t)n * VD] = y;
    vs += y;
  }
  vsum[(size_t)bt * VD + d] = vs;
}

// ------- shared: s[n]=tanh(sum_h Cm[bt,n,h]*gate[bt,h]*wv[h] + b); softmax over n;
//         out[bt,d] = sum_n m[n]*Vmat[bt,n,d]  (optionally * (1+BETA*sigmoid(saf)))
__global__ __launch_bounds__(256) void k_score_einsum(
    const float* __restrict__ Cm, const float* __restrict__ gate,
    const float* __restrict__ wvv, const float* __restrict__ bsc,
    const float* __restrict__ Vmat, const float* __restrict__ saf_in,
    float* __restrict__ outp) {
  const int bt = blockIdx.x, t = threadIdx.x;
  __shared__ float us[HD];
  __shared__ float sc[NSP];
  __shared__ float mp[NSP + 1];
  us[t] = gate[(size_t)bt * HD + t] * wvv[t];
  __syncthreads();
  const int lane = t & 63, w = t >> 6;
  const float bias0 = bsc[0];
  for (int n = w; n < NSP; n += 4) {
    const float* row = Cm + ((size_t)bt * NSP + n) * HD;
    float s = 0.f;
#pragma unroll
    for (int i = 0; i < HD / 64; ++i) s = fmaf(row[lane + 64 * i], us[lane + 64 * i], s);
    for (int off = 32; off; off >>= 1) s += __shfl_down(s, off);
    if (lane == 0) sc[n] = tanhf(s + bias0);
  }
  __syncthreads();
  if (t == 0) {
    float mx = -1e30f;
    for (int n = 0; n < NSP; ++n) mx = fmaxf(mx, sc[n]);
    float sum = 0.f;
    for (int n = 0; n < NSP; ++n) { float e = __expf(sc[n] - mx); mp[n] = e; sum += e; }
    float inv = 1.f / sum;
    for (int n = 0; n < NSP; ++n) mp[n] *= inv;
  }
  __syncthreads();
  for (int d = t; d < VD; d += 256) {
    const float* vp = Vmat + (size_t)bt * NSP * VD + d;
    float a = 0.f;
#pragma unroll
    for (int n = 0; n < NSP; ++n) a = fmaf(mp[n], vp[(size_t)n * VD], a);
    if (saf_in) {
      const float sg = 1.f / (1.f + __expf(-saf_in[(size_t)bt * VD + d]));
      a *= (1.f + BETA * sg);
    }
    outp[(size_t)bt * VD + d] = a;
  }
}

// ---------------- tmean[bt,d] = aq1[bt,d] * mean_n vq1[bt,n,d] --------------------
__global__ __launch_bounds__(512) void k_vq1mean(const float* __restrict__ vq1,
                                                 const float* __restrict__ aq1,
                                                 float* __restrict__ tmean) {
  const int bt = blockIdx.x, d = threadIdx.x;
  const float* p = vq1 + (size_t)bt * NSP * VD + d;
  float s = 0.f;
#pragma unroll
  for (int n = 0; n < NSP; ++n) s += p[(size_t)n * VD];
  tmean[(size_t)bt * VD + d] = s * (1.f / 49.f) * aq1[(size_t)bt * VD + d];
}

// ---------------- c_att = video * (ch+1) ------------------------------------------
__global__ __launch_bounds__(256) void k_catt(const float* __restrict__ video,
                                              const float* __restrict__ ch,
                                              float* __restrict__ c_att) {
  const size_t i = ((size_t)blockIdx.x * 256 + threadIdx.x) * 4;
  const size_t bt = i / ((size_t)NSP * VD);
  const int d = (int)(i & (VD - 1));
  float4 vv = *(const float4*)(video + i);
  const float4 cv = *(const float4*)(ch + bt * VD + d);
  vv.x *= (cv.x + 1.f); vv.y *= (cv.y + 1.f);
  vv.z *= (cv.z + 1.f); vv.w *= (cv.w + 1.f);
  *(float4*)(c_att + i) = vv;
}

extern "C" void kernel_launch(void* const* d_in, const int* in_sizes, int n_in,
                              void* d_out, int out_size, void* d_ws, size_t ws_size,
                              hipStream_t stream) {
  const float* video  = (const float*)d_in[0];
  const float* audio  = (const float*)d_in[1];
  const float* wq     = (const float*)d_in[2];  const float* bq     = (const float*)d_in[3];
  const float* wk     = (const float*)d_in[4];  const float* bk     = (const float*)d_in[5];
  const float* wv     = (const float*)d_in[6];  const float* bv     = (const float*)d_in[7];
  const float* ln_g   = (const float*)d_in[8];  const float* ln_b   = (const float*)d_in[9];
  const float* w_ave  = (const float*)d_in[10]; const float* b_ave  = (const float*)d_in[11];
  const float* w_v3   = (const float*)d_in[12]; const float* b_v3   = (const float*)d_in[13];
  const float* w_avatt= (const float*)d_in[14]; const float* b_avatt= (const float*)d_in[15];
  const float* w_a1   = (const float*)d_in[16]; const float* b_a1   = (const float*)d_in[17];
  const float* w_v1   = (const float*)d_in[18]; const float* b_v1   = (const float*)d_in[19];
  const float* w_bn   = (const float*)d_in[20]; const float* b_bn   = (const float*)d_in[21];
  const float* w_ca   = (const float*)d_in[22]; const float* b_ca   = (const float*)d_in[23];
  const float* w_v2   = (const float*)d_in[24]; const float* b_v2   = (const float*)d_in[25];
  const float* w_a2   = (const float*)d_in[26]; const float* b_a2   = (const float*)d_in[27];
  const float* w_sa   = (const float*)d_in[28]; const float* b_sa   = (const float*)d_in[29];

  float* out = (float*)d_out;
  float* out_audio = out + (size_t)BT * VD;  // raw_audio_feature region

  // workspace layout (floats); total ~169.1M floats = ~645 MiB
  float* ws    = (float*)d_ws;
  float* q_    = ws;
  float* k_    = q_    + (size_t)BT * NSP * QD;
  float* v_    = k_    + (size_t)BT * NSP * QD;
  float* vf2   = v_    + (size_t)BT * NSP * VD;
  float* vsum  = vf2   + (size_t)BT * NSP * VD;
  float* vavg  = vsum  + (size_t)BT * VD;
  float* aq1   = vavg  + (size_t)BT * HD;
  float* aq2   = aq1   + (size_t)BT * VD;
  float* tmean = aq2   + (size_t)BT * HD;
  float* avq   = tmean + (size_t)BT * VD;
  float* saf   = avq   + (size_t)BT * HD;
  float* ch    = saf   + (size_t)BT * VD;
  // reuse (lifetime-disjoint):
  float* C1   = q_;    // [M,HD] after attn (overwrites q,k)
  float* vq1  = v_;    // [M,VD] after attn (overwrites v)
  float* catt = vf2;   // [M,VD] after all vf2 consumers
  float* C2   = q_;    // [M,HD] after C1 consumed

  const int M = BT * NSP;  // 125440
  const dim3 blk(256);

  k_audio<<<BT, AD, 0, stream>>>(audio, out_audio);

  // QKV projections
  k_gemm<0><<<dim3(QD / 128, M / 128), blk, 0, stream>>>(video, wq, bq, q_, M, QD, VD, 1.f);
  k_gemm<0><<<dim3(QD / 128, M / 128), blk, 0, stream>>>(video, wk, bk, k_, M, QD, VD, 1.f);
  k_gemm<0><<<dim3(VD / 128, M / 128), blk, 0, stream>>>(video, wv, bv, v_, M, VD, VD, 1.f);
  k_attn<<<BT, 512, 0, stream>>>(q_, k_, v_, video, ln_g, ln_b, vf2, vsum);

  // small GEMMs
  k_gemm<1><<<dim3(HD / 128, BT / 128), blk, 0, stream>>>(vsum, w_ave, b_ave, vavg, BT, HD, VD, 1.f / 49.f);
  k_gemm<1><<<dim3(VD / 128, BT / 128), blk, 0, stream>>>(out_audio, w_a1, b_a1, aq1, BT, VD, AD, 1.f);
  k_gemm<1><<<dim3(HD / 128, BT / 128), blk, 0, stream>>>(out_audio, w_a2, b_a2, aq2, BT, HD, AD, 1.f);

  // self spatial attention branch
  k_gemm<1><<<dim3(HD / 128, M / 128), blk, 0, stream>>>(vf2, w_v3, b_v3, C1, M, HD, VD, 1.f);
  k_score_einsum<<<BT, 256, 0, stream>>>(C1, vavg, w_avatt, b_avatt, vf2, nullptr, saf);

  // audio-guided channel attention
  k_gemm<1><<<dim3(VD / 128, M / 128), blk, 0, stream>>>(vf2, w_v1, b_v1, vq1, M, VD, VD, 1.f);
  k_vq1mean<<<BT, VD, 0, stream>>>(vq1, aq1, tmean);
  k_gemm<1><<<dim3(HD / 128, BT / 128), blk, 0, stream>>>(tmean, w_bn, b_bn, avq, BT, HD, VD, 1.f);
  k_gemm<2><<<dim3(VD / 128, BT / 128), blk, 0, stream>>>(avq, w_ca, b_ca, ch, BT, VD, HD, 1.f);
  k_catt<<<(BT * NSP * VD) / 1024, 256, 0, stream>>>(video, ch, catt);

  // audio-guided spatial attention + final combine
  k_gemm<1><<<dim3(HD / 128, M / 128), blk, 0, stream>>>(catt, w_v2, b_v2, C2, M, HD, VD, 1.f);
  k_score_einsum<<<BT, 256, 0, stream>>>(C2, aq2, w_sa, b_sa, catt, saf, out);
}

// Round 2
// 2396.722 us; speedup vs baseline: 1.6680x; 1.6680x over previous
//
#include <hip/hip_runtime.h>

#define B_   256
#define T_   10
#define BT   2560
#define NSP  49
#define VD   512
#define AD   128
#define HD   256
#define QD   128
#define BETA 0.5f

typedef __bf16 bf16_t;
typedef bf16_t bf16x8 __attribute__((ext_vector_type(8)));
typedef float  f32x4  __attribute__((ext_vector_type(4)));

#define GLDS(g, l) __builtin_amdgcn_global_load_lds(                          \
    (const __attribute__((address_space(1))) void*)(g),                       \
    (__attribute__((address_space(3))) void*)(l), 16, 0, 0)

// ---------------- audio transpose: [T,B,AD] -> [B,T,AD] ---------------------------
__global__ __launch_bounds__(128) void k_audio(const float* __restrict__ audio,
                                               float* __restrict__ out2) {
  int bt = blockIdx.x;
  int b = bt / T_, t = bt - b * T_;
  out2[(size_t)bt * AD + threadIdx.x] = audio[((size_t)t * B_ + b) * AD + threadIdx.x];
}

// ---------------- fp32 -> bf16 hi/lo split, 8 elems/thread ------------------------
__global__ __launch_bounds__(256) void k_split(const float* __restrict__ x,
                                               bf16_t* __restrict__ hi,
                                               bf16_t* __restrict__ lo) {
  const size_t i8 = (size_t)blockIdx.x * 256 + threadIdx.x;
  const float4 x0 = ((const float4*)x)[2 * i8];
  const float4 x1 = ((const float4*)x)[2 * i8 + 1];
  const float xs[8] = {x0.x, x0.y, x0.z, x0.w, x1.x, x1.y, x1.z, x1.w};
  bf16x8 h, l;
#pragma unroll
  for (int j = 0; j < 8; ++j) {
    const bf16_t hb = (bf16_t)xs[j];
    h[j] = hb;
    l[j] = (bf16_t)(xs[j] - (float)hb);
  }
  ((bf16x8*)hi)[i8] = h;
  ((bf16x8*)lo)[i8] = l;
}

// ---------------- split-bf16 MFMA GEMM: C = act(Ahi+Alo @ (Whi+Wlo)^T + bias) -----
// A planes [M,K] bf16, W planes [N,K] bf16, C [M,N] fp32. M%128==0, N%128==0, K%32==0.
// 128x128 tile, BK=32, 256 threads (4 waves, 2x2), 16x16x32 MFMA, 3 passes.
__device__ __forceinline__ bf16x8 ldsread(const unsigned char* plane, int rblk, int lane) {
  const int row = (rblk << 4) + (lane & 15);
  const int chunk = (lane >> 4) ^ ((row >> 1) & 3);
  return *(const bf16x8*)(plane + row * 64 + chunk * 16);
}

template <int ACT>  // 0 none, 1 relu
__global__ __launch_bounds__(256, 2) void k_mgemm(
    const bf16_t* __restrict__ Ahi, const bf16_t* __restrict__ Alo,
    const bf16_t* __restrict__ Whi, const bf16_t* __restrict__ Wlo,
    const float* __restrict__ bias, float* __restrict__ C,
    int M, int N, int K) {
  __shared__ __align__(16) unsigned char smem[2][4][8192];
  const int t = threadIdx.x;
  const int lane = t & 63, wid = t >> 6;
  const int wr = wid >> 1, wc = wid & 1;
  const int rowBase = blockIdx.y * 128;
  const int colBase = blockIdx.x * 128;

  f32x4 acc[4][4] = {};

  const bf16_t* srcs[4] = {Ahi, Alo, Whi, Wlo};
  const int rb[4] = {rowBase, rowBase, colBase, colBase};

  auto stage = [&](int buf, int kt) {
    const int k0 = kt << 5;
#pragma unroll
    for (int p = 0; p < 4; ++p) {
#pragma unroll
      for (int issue = 0; issue < 2; ++issue) {
        const int orow = issue * 64 + wid * 16 + (lane >> 2);
        const int sc = (lane & 3) ^ ((orow >> 1) & 3);
        const bf16_t* g = srcs[p] + (size_t)(rb[p] + orow) * K + k0 + sc * 8;
        unsigned char* l = &smem[buf][p][issue * 4096 + wid * 1024];
        GLDS(g, l);
      }
    }
  };

  const int NK = K >> 5;
  stage(0, 0);
  for (int kt = 0; kt < NK; ++kt) {
    const int cur = kt & 1;
    __syncthreads();
    if (kt + 1 < NK) stage(cur ^ 1, kt + 1);
    const unsigned char* pa_hi = smem[cur][0];
    const unsigned char* pa_lo = smem[cur][1];
    const unsigned char* pw_hi = smem[cur][2];
    const unsigned char* pw_lo = smem[cur][3];
    bf16x8 ah[4], al[4], bh[4], bl[4];
#pragma unroll
    for (int m = 0; m < 4; ++m) {
      ah[m] = ldsread(pa_hi, wr * 4 + m, lane);
      al[m] = ldsread(pa_lo, wr * 4 + m, lane);
    }
#pragma unroll
    for (int n = 0; n < 4; ++n) {
      bh[n] = ldsread(pw_hi, wc * 4 + n, lane);
      bl[n] = ldsread(pw_lo, wc * 4 + n, lane);
    }
#pragma unroll
    for (int m = 0; m < 4; ++m)
#pragma unroll
      for (int n = 0; n < 4; ++n) {
        acc[m][n] = __builtin_amdgcn_mfma_f32_16x16x32_bf16(ah[m], bh[n], acc[m][n], 0, 0, 0);
        acc[m][n] = __builtin_amdgcn_mfma_f32_16x16x32_bf16(ah[m], bl[n], acc[m][n], 0, 0, 0);
        acc[m][n] = __builtin_amdgcn_mfma_f32_16x16x32_bf16(al[m], bh[n], acc[m][n], 0, 0, 0);
      }
  }

  const int r4 = lane >> 4;   // 0..3
  const int cn = lane & 15;
#pragma unroll
  for (int n = 0; n < 4; ++n) {
    const int col = colBase + wc * 64 + n * 16 + cn;
    const float bb = bias[col];
#pragma unroll
    for (int m = 0; m < 4; ++m) {
      const int row0 = rowBase + wr * 64 + m * 16 + r4 * 4;
#pragma unroll
      for (int r = 0; r < 4; ++r) {
        float x = acc[m][n][r] + bb;
        if (ACT == 1) x = fmaxf(x, 0.f);
        C[(size_t)(row0 + r) * N + col] = x;
      }
    }
  }
}

// ---------------- generic fp32 GEMM (small M): C = act(alpha*(A@W^T)+bias) --------
template <int ACT>  // 0 none, 1 relu, 2 sigmoid
__global__ __launch_bounds__(256) void k_gemm(const float* __restrict__ A,
                                              const float* __restrict__ W,
                                              const float* __restrict__ bias,
                                              float* __restrict__ C,
                                              int M, int N, int K, float alpha) {
  __shared__ __align__(16) float As[8][132];
  __shared__ __align__(16) float Ws[8][132];
  const int t = threadIdx.x;
  const int tx = t & 15, ty = t >> 4;
  const int rowBase = blockIdx.y * 128;
  const int colBase = blockIdx.x * 128;
  const int lrow = t >> 1, lq = t & 1;
  const float* Ap = A + (size_t)(rowBase + lrow) * K + lq * 4;
  const float* Wp = W + (size_t)(colBase + lrow) * K + lq * 4;
  float acc[8][8] = {};
  for (int k0 = 0; k0 < K; k0 += 8) {
    const float4 av = *(const float4*)(Ap + k0);
    const float4 wv = *(const float4*)(Wp + k0);
    __syncthreads();
    As[lq * 4 + 0][lrow] = av.x; As[lq * 4 + 1][lrow] = av.y;
    As[lq * 4 + 2][lrow] = av.z; As[lq * 4 + 3][lrow] = av.w;
    Ws[lq * 4 + 0][lrow] = wv.x; Ws[lq * 4 + 1][lrow] = wv.y;
    Ws[lq * 4 + 2][lrow] = wv.z; Ws[lq * 4 + 3][lrow] = wv.w;
    __syncthreads();
#pragma unroll
    for (int kk = 0; kk < 8; ++kk) {
      const float4 a0 = *(const float4*)&As[kk][ty * 8];
      const float4 a1 = *(const float4*)&As[kk][ty * 8 + 4];
      const float4 w0 = *(const float4*)&Ws[kk][tx * 8];
      const float4 w1 = *(const float4*)&Ws[kk][tx * 8 + 4];
      const float a_[8] = {a0.x, a0.y, a0.z, a0.w, a1.x, a1.y, a1.z, a1.w};
      const float w_[8] = {w0.x, w0.y, w0.z, w0.w, w1.x, w1.y, w1.z, w1.w};
#pragma unroll
      for (int i = 0; i < 8; ++i)
#pragma unroll
        for (int j = 0; j < 8; ++j)
          acc[i][j] = fmaf(a_[i], w_[j], acc[i][j]);
    }
  }
  const float4 b0 = *(const float4*)(bias + colBase + tx * 8);
  const float4 b1 = *(const float4*)(bias + colBase + tx * 8 + 4);
  const float bb[8] = {b0.x, b0.y, b0.z, b0.w, b1.x, b1.y, b1.z, b1.w};
#pragma unroll
  for (int i = 0; i < 8; ++i) {
    float* crow = C + (size_t)(rowBase + ty * 8 + i) * N + colBase + tx * 8;
    float o[8];
#pragma unroll
    for (int j = 0; j < 8; ++j) {
      float x = acc[i][j] * alpha + bb[j];
      if (ACT == 1) x = fmaxf(x, 0.f);
      if (ACT == 2) x = 1.f / (1.f + __expf(-x));
      o[j] = x;
    }
    *(float4*)(crow)     = make_float4(o[0], o[1], o[2], o[3]);
    *(float4*)(crow + 4) = make_float4(o[4], o[5], o[6], o[7]);
  }
}

// ---------------- per-bt attention: softmax(qk^T)@v + residual + LN + row-sum -----
// writes LN output as bf16 hi/lo planes + fp32 row-sum
__global__ __launch_bounds__(512) void k_attn(const float* __restrict__ q,
                                              const float* __restrict__ k,
                                              const float* __restrict__ v,
                                              const float* __restrict__ vf,
                                              const float* __restrict__ ln_g,
                                              const float* __restrict__ ln_b,
                                              bf16_t* __restrict__ vf2hi,
                                              bf16_t* __restrict__ vf2lo,
                                              float* __restrict__ vsum) {
  const int bt = blockIdx.x;
  const int t = threadIdx.x;
  __shared__ float qs[NSP][129];
  __shared__ float ks[NSP][129];
  __shared__ float at[NSP][50];
  __shared__ float red[2][NSP][8];
  __shared__ float mu_s[NSP], rs_s[NSP];

  const float* qg = q + (size_t)bt * NSP * QD;
  const float* kg = k + (size_t)bt * NSP * QD;
  for (int i = t; i < NSP * QD; i += 512) {
    int n = i >> 7, c = i & (QD - 1);
    qs[n][c] = qg[i];
    ks[n][c] = kg[i];
  }
  __syncthreads();
  for (int p = t; p < NSP * NSP; p += 512) {
    int n = p / NSP, m = p - n * NSP;
    float s = 0.f;
#pragma unroll 16
    for (int j = 0; j < QD; ++j) s = fmaf(qs[n][j], ks[m][j], s);
    at[n][m] = s;
  }
  __syncthreads();
  if (t < NSP) {
    float mx = -1e30f;
    for (int m2 = 0; m2 < NSP; ++m2) mx = fmaxf(mx, at[t][m2]);
    float sum = 0.f;
    for (int m2 = 0; m2 < NSP; ++m2) { float e = __expf(at[t][m2] - mx); at[t][m2] = e; sum += e; }
    float inv = 1.f / sum;
    for (int m2 = 0; m2 < NSP; ++m2) at[t][m2] *= inv;
  }
  __syncthreads();
  const int d = t;  // 0..511
  const float* vg  = v  + (size_t)bt * NSP * VD + d;
  const float* vfg = vf + (size_t)bt * NSP * VD + d;
  float xv[NSP] = {};
  for (int m2 = 0; m2 < NSP; ++m2) {
    const float vm = vg[(size_t)m2 * VD];
#pragma unroll
    for (int n = 0; n < NSP; ++n) xv[n] = fmaf(at[n][m2], vm, xv[n]);
  }
#pragma unroll
  for (int n = 0; n < NSP; ++n) xv[n] += vfg[(size_t)n * VD];
  const int lane = t & 63, wid = t >> 6;
#pragma unroll
  for (int n = 0; n < NSP; ++n) {
    float s1 = xv[n], s2 = xv[n] * xv[n];
    for (int off = 32; off; off >>= 1) { s1 += __shfl_down(s1, off); s2 += __shfl_down(s2, off); }
    if (lane == 0) { red[0][n][wid] = s1; red[1][n][wid] = s2; }
  }
  __syncthreads();
  if (t < NSP) {
    float s1 = 0.f, s2 = 0.f;
    for (int w2 = 0; w2 < 8; ++w2) { s1 += red[0][t][w2]; s2 += red[1][t][w2]; }
    const float mu = s1 * (1.f / VD);
    const float var = s2 * (1.f / VD) - mu * mu;
    mu_s[t] = mu;
    rs_s[t] = rsqrtf(var + 1e-5f);
  }
  __syncthreads();
  const float gd = ln_g[d], bd = ln_b[d];
  bf16_t* oh = vf2hi + (size_t)bt * NSP * VD + d;
  bf16_t* ol = vf2lo + (size_t)bt * NSP * VD + d;
  float vs = 0.f;
#pragma unroll
  for (int n = 0; n < NSP; ++n) {
    const float y = (xv[n] - mu_s[n]) * rs_s[n] * gd + bd;
    const bf16_t hb = (bf16_t)y;
    oh[(size_t)n * VD] = hb;
    ol[(size_t)n * VD] = (bf16_t)(y - (float)hb);
    vs += y;
  }
  vsum[(size_t)bt * VD + d] = vs;
}

// ------- shared: s[n]=tanh(sum_h Cm[bt,n,h]*gate[bt,h]*wv[h] + b); softmax over n;
//         out[bt,d] = sum_n m[n]*(Vhi+Vlo)[bt,n,d]  (opt * (1+BETA*sigmoid(saf)))
__global__ __launch_bounds__(256) void k_score_einsum(
    const float* __restrict__ Cm, const float* __restrict__ gate,
    const float* __restrict__ wvv, const float* __restrict__ bsc,
    const bf16_t* __restrict__ Vhi, const bf16_t* __restrict__ Vlo,
    const float* __restrict__ saf_in, float* __restrict__ outp) {
  const int bt = blockIdx.x, t = threadIdx.x;
  __shared__ float us[HD];
  __shared__ float sc[NSP];
  __shared__ float mp[NSP + 1];
  us[t] = gate[(size_t)bt * HD + t] * wvv[t];
  __syncthreads();
  const int lane = t & 63, w = t >> 6;
  const float bias0 = bsc[0];
  for (int n = w; n < NSP; n += 4) {
    const float* row = Cm + ((size_t)bt * NSP + n) * HD;
    float s = 0.f;
#pragma unroll
    for (int i = 0; i < HD / 64; ++i) s = fmaf(row[lane + 64 * i], us[lane + 64 * i], s);
    for (int off = 32; off; off >>= 1) s += __shfl_down(s, off);
    if (lane == 0) sc[n] = tanhf(s + bias0);
  }
  __syncthreads();
  if (t == 0) {
    float mx = -1e30f;
    for (int n = 0; n < NSP; ++n) mx = fmaxf(mx, sc[n]);
    float sum = 0.f;
    for (int n = 0; n < NSP; ++n) { float e = __expf(sc[n] - mx); mp[n] = e; sum += e; }
    float inv = 1.f / sum;
    for (int n = 0; n < NSP; ++n) mp[n] *= inv;
  }
  __syncthreads();
  for (int d = t; d < VD; d += 256) {
    const bf16_t* vh = Vhi + (size_t)bt * NSP * VD + d;
    const bf16_t* vl = Vlo + (size_t)bt * NSP * VD + d;
    float a = 0.f;
#pragma unroll
    for (int n = 0; n < NSP; ++n) {
      const float vv = (float)vh[(size_t)n * VD] + (float)vl[(size_t)n * VD];
      a = fmaf(mp[n], vv, a);
    }
    if (saf_in) {
      const float sg = 1.f / (1.f + __expf(-saf_in[(size_t)bt * VD + d]));
      a *= (1.f + BETA * sg);
    }
    outp[(size_t)bt * VD + d] = a;
  }
}

// ---------------- tmean[bt,d] = aq1[bt,d] * mean_n vq1[bt,n,d] --------------------
__global__ __launch_bounds__(512) void k_vq1mean(const float* __restrict__ vq1,
                                                 const float* __restrict__ aq1,
                                                 float* __restrict__ tmean) {
  const int bt = blockIdx.x, d = threadIdx.x;
  const float* p = vq1 + (size_t)bt * NSP * VD + d;
  float s = 0.f;
#pragma unroll
  for (int n = 0; n < NSP; ++n) s += p[(size_t)n * VD];
  tmean[(size_t)bt * VD + d] = s * (1.f / 49.f) * aq1[(size_t)bt * VD + d];
}

// ---------------- c_att = video * (ch+1) -> bf16 hi/lo planes ---------------------
__global__ __launch_bounds__(256) void k_catt(const float* __restrict__ video,
                                              const float* __restrict__ ch,
                                              bf16_t* __restrict__ hi,
                                              bf16_t* __restrict__ lo) {
  const size_t i8 = (size_t)blockIdx.x * 256 + threadIdx.x;
  const size_t i = i8 * 8;
  const size_t bt = i / ((size_t)NSP * VD);
  const int d = (int)(i & (VD - 1));
  const float4 v0 = ((const float4*)(video + i))[0];
  const float4 v1 = ((const float4*)(video + i))[1];
  const float4 c0 = *(const float4*)(ch + bt * VD + d);
  const float4 c1 = *(const float4*)(ch + bt * VD + d + 4);
  const float xs[8] = {v0.x * (c0.x + 1.f), v0.y * (c0.y + 1.f),
                       v0.z * (c0.z + 1.f), v0.w * (c0.w + 1.f),
                       v1.x * (c1.x + 1.f), v1.y * (c1.y + 1.f),
                       v1.z * (c1.z + 1.f), v1.w * (c1.w + 1.f)};
  bf16x8 h, l;
#pragma unroll
  for (int j = 0; j < 8; ++j) {
    const bf16_t hb = (bf16_t)xs[j];
    h[j] = hb;
    l[j] = (bf16_t)(xs[j] - (float)hb);
  }
  ((bf16x8*)hi)[i8] = h;
  ((bf16x8*)lo)[i8] = l;
}

extern "C" void kernel_launch(void* const* d_in, const int* in_sizes, int n_in,
                              void* d_out, int out_size, void* d_ws, size_t ws_size,
                              hipStream_t stream) {
  const float* video  = (const float*)d_in[0];
  const float* audio  = (const float*)d_in[1];
  const float* wq     = (const float*)d_in[2];  const float* bq     = (const float*)d_in[3];
  const float* wk     = (const float*)d_in[4];  const float* bk     = (const float*)d_in[5];
  const float* wv     = (const float*)d_in[6];  const float* bv     = (const float*)d_in[7];
  const float* ln_g   = (const float*)d_in[8];  const float* ln_b   = (const float*)d_in[9];
  const float* w_ave  = (const float*)d_in[10]; const float* b_ave  = (const float*)d_in[11];
  const float* w_v3   = (const float*)d_in[12]; const float* b_v3   = (const float*)d_in[13];
  const float* w_avatt= (const float*)d_in[14]; const float* b_avatt= (const float*)d_in[15];
  const float* w_a1   = (const float*)d_in[16]; const float* b_a1   = (const float*)d_in[17];
  const float* w_v1   = (const float*)d_in[18]; const float* b_v1   = (const float*)d_in[19];
  const float* w_bn   = (const float*)d_in[20]; const float* b_bn   = (const float*)d_in[21];
  const float* w_ca   = (const float*)d_in[22]; const float* b_ca   = (const float*)d_in[23];
  const float* w_v2   = (const float*)d_in[24]; const float* b_v2   = (const float*)d_in[25];
  const float* w_a2   = (const float*)d_in[26]; const float* b_a2   = (const float*)d_in[27];
  const float* w_sa   = (const float*)d_in[28]; const float* b_sa   = (const float*)d_in[29];

  float* out = (float*)d_out;
  float* out_audio = out + (size_t)BT * VD;

  const size_t M = (size_t)BT * NSP;  // 125440

  // ---- workspace carve (bytes) ----
  unsigned char* p = (unsigned char*)d_ws;
  auto carve = [&](size_t bytes) { unsigned char* r = p; p += (bytes + 255) & ~(size_t)255; return r; };
  bf16_t* vhi = (bf16_t*)carve(M * VD * 2);       // reused as vf2hi, then catthi
  bf16_t* vlo = (bf16_t*)carve(M * VD * 2);       // reused as vf2lo, then cattlo
  bf16_t* wqh = (bf16_t*)carve((size_t)QD * VD * 2);
  bf16_t* wql = (bf16_t*)carve((size_t)QD * VD * 2);
  bf16_t* wkh = (bf16_t*)carve((size_t)QD * VD * 2);
  bf16_t* wkl = (bf16_t*)carve((size_t)QD * VD * 2);
  bf16_t* wvh = (bf16_t*)carve((size_t)VD * VD * 2);
  bf16_t* wvl = (bf16_t*)carve((size_t)VD * VD * 2);
  bf16_t* w3h = (bf16_t*)carve((size_t)HD * VD * 2);
  bf16_t* w3l = (bf16_t*)carve((size_t)HD * VD * 2);
  bf16_t* w1h = (bf16_t*)carve((size_t)VD * VD * 2);
  bf16_t* w1l = (bf16_t*)carve((size_t)VD * VD * 2);
  bf16_t* w2h = (bf16_t*)carve((size_t)HD * VD * 2);
  bf16_t* w2l = (bf16_t*)carve((size_t)HD * VD * 2);
  float* q_   = (float*)carve(M * QD * 4);        // q_..k_ region reused as C1 / C2 [M,HD]
  float* k_   = (float*)carve(M * QD * 4);
  float* v_   = (float*)carve(M * VD * 4);        // reused as vq1
  float* vsum = (float*)carve((size_t)BT * VD * 4);
  float* vavg = (float*)carve((size_t)BT * HD * 4);
  float* aq1  = (float*)carve((size_t)BT * VD * 4);
  float* aq2  = (float*)carve((size_t)BT * HD * 4);
  float* tmean= (float*)carve((size_t)BT * VD * 4);
  float* avq  = (float*)carve((size_t)BT * HD * 4);
  float* saf  = (float*)carve((size_t)BT * VD * 4);
  float* ch   = (float*)carve((size_t)BT * VD * 4);
  float* C1   = q_;
  float* vq1  = v_;
  float* C2   = q_;
  bf16_t *vf2hi = vhi, *vf2lo = vlo, *catthi = vhi, *cattlo = vlo;

  const dim3 blk(256);

  k_audio<<<BT, AD, 0, stream>>>(audio, out_audio);

  // split video + weights into bf16 hi/lo planes
  k_split<<<(int)(M * VD / 8 / 256), blk, 0, stream>>>(video, vhi, vlo);
  k_split<<<QD * VD / 8 / 256, blk, 0, stream>>>(wq, wqh, wql);
  k_split<<<QD * VD / 8 / 256, blk, 0, stream>>>(wk, wkh, wkl);
  k_split<<<VD * VD / 8 / 256, blk, 0, stream>>>(wv, wvh, wvl);
  k_split<<<HD * VD / 8 / 256, blk, 0, stream>>>(w_v3, w3h, w3l);
  k_split<<<VD * VD / 8 / 256, blk, 0, stream>>>(w_v1, w1h, w1l);
  k_split<<<HD * VD / 8 / 256, blk, 0, stream>>>(w_v2, w2h, w2l);

  // QKV projections (MFMA split-bf16)
  k_mgemm<0><<<dim3(QD / 128, M / 128), blk, 0, stream>>>(vhi, vlo, wqh, wql, bq, q_, M, QD, VD);
  k_mgemm<0><<<dim3(QD / 128, M / 128), blk, 0, stream>>>(vhi, vlo, wkh, wkl, bk, k_, M, QD, VD);
  k_mgemm<0><<<dim3(VD / 128, M / 128), blk, 0, stream>>>(vhi, vlo, wvh, wvl, bv, v_, M, VD, VD);
  k_attn<<<BT, 512, 0, stream>>>(q_, k_, v_, video, ln_g, ln_b, vf2hi, vf2lo, vsum);

  // small fp32 GEMMs
  k_gemm<1><<<dim3(HD / 128, BT / 128), blk, 0, stream>>>(vsum, w_ave, b_ave, vavg, BT, HD, VD, 1.f / 49.f);
  k_gemm<1><<<dim3(VD / 128, BT / 128), blk, 0, stream>>>(out_audio, w_a1, b_a1, aq1, BT, VD, AD, 1.f);
  k_gemm<1><<<dim3(HD / 128, BT / 128), blk, 0, stream>>>(out_audio, w_a2, b_a2, aq2, BT, HD, AD, 1.f);

  // self spatial attention branch
  k_mgemm<1><<<dim3(HD / 128, M / 128), blk, 0, stream>>>(vf2hi, vf2lo, w3h, w3l, b_v3, C1, M, HD, VD);
  k_score_einsum<<<BT, 256, 0, stream>>>(C1, vavg, w_avatt, b_avatt, vf2hi, vf2lo, nullptr, saf);

  // audio-guided channel attention
  k_mgemm<1><<<dim3(VD / 128, M / 128), blk, 0, stream>>>(vf2hi, vf2lo, w1h, w1l, b_v1, vq1, M, VD, VD);
  k_vq1mean<<<BT, VD, 0, stream>>>(vq1, aq1, tmean);
  k_gemm<1><<<dim3(HD / 128, BT / 128), blk, 0, stream>>>(tmean, w_bn, b_bn, avq, BT, HD, VD, 1.f);
  k_gemm<2><<<dim3(VD / 128, BT / 128), blk, 0, stream>>>(avq, w_ca, b_ca, ch, BT, VD, HD, 1.f);
  k_catt<<<(int)(M * VD / 8 / 256), blk, 0, stream>>>(video, ch, catthi, cattlo);

  // audio-guided spatial attention + final combine
  k_mgemm<1><<<dim3(HD / 128, M / 128), blk, 0, stream>>>(catthi, cattlo, w2h, w2l, b_v2, C2, M, HD, VD);
  k_score_einsum<<<BT, 256, 0, stream>>>(C2, aq2, w_sa, b_sa, catthi, cattlo, saf, out);
}

// Round 3
// 2213.652 us; speedup vs baseline: 1.8059x; 1.0827x over previous
//
#include <hip/hip_runtime.h>

#define B_   256
#define T_   10
#define BT   2560
#define NSP  49
#define VD   512
#define AD   128
#define HD   256
#define QD   128
#define BETA 0.5f

typedef __bf16 bf16_t;
typedef bf16_t bf16x8 __attribute__((ext_vector_type(8)));
typedef float  f32x4  __attribute__((ext_vector_type(4)));

#define GLDS(g, l) __builtin_amdgcn_global_load_lds(                          \
    (const __attribute__((address_space(1))) void*)(g),                       \
    (__attribute__((address_space(3))) void*)(l), 16, 0, 0)
#define MFMA16(a, b, c) __builtin_amdgcn_mfma_f32_16x16x32_bf16(a, b, c, 0, 0, 0)

// ---------------- audio transpose: [T,B,AD] -> [B,T,AD] ---------------------------
__global__ __launch_bounds__(128) void k_audio(const float* __restrict__ audio,
                                               float* __restrict__ out2) {
  int bt = blockIdx.x;
  int b = bt / T_, t = bt - b * T_;
  out2[(size_t)bt * AD + threadIdx.x] = audio[((size_t)t * B_ + b) * AD + threadIdx.x];
}

// ---------------- concat bias [bq|bk|bv] -> bcat[768] -----------------------------
__global__ __launch_bounds__(256) void k_bcat(const float* __restrict__ bq,
                                              const float* __restrict__ bk,
                                              const float* __restrict__ bv,
                                              float* __restrict__ bcat) {
  int t = blockIdx.x * 256 + threadIdx.x;
  if (t < 128) bcat[t] = bq[t];
  else if (t < 256) bcat[t] = bk[t - 128];
  else if (t < 768) bcat[t] = bv[t - 256];
}

// ---------------- fp32 -> bf16 hi/lo split, 8 elems/thread ------------------------
__global__ __launch_bounds__(256) void k_split(const float* __restrict__ x,
                                               bf16_t* __restrict__ hi,
                                               bf16_t* __restrict__ lo) {
  const size_t i8 = (size_t)blockIdx.x * 256 + threadIdx.x;
  const float4 x0 = ((const float4*)x)[2 * i8];
  const float4 x1 = ((const float4*)x)[2 * i8 + 1];
  const float xs[8] = {x0.x, x0.y, x0.z, x0.w, x1.x, x1.y, x1.z, x1.w};
  bf16x8 h, l;
#pragma unroll
  for (int j = 0; j < 8; ++j) {
    const bf16_t hb = (bf16_t)xs[j];
    h[j] = hb;
    l[j] = (bf16_t)(xs[j] - (float)hb);
  }
  ((bf16x8*)hi)[i8] = h;
  ((bf16x8*)lo)[i8] = l;
}

// ---------------- split-bf16 MFMA GEMM ------------------------------------------
// OUT=0: C fp32.  OUT=1: Chi/Clo split-bf16 planes.  ACT: 0 none, 1 relu.
__device__ __forceinline__ bf16x8 ldsread(const unsigned char* plane, int rblk, int lane) {
  const int row = (rblk << 4) + (lane & 15);
  const int chunk = (lane >> 4) ^ ((row >> 1) & 3);
  return *(const bf16x8*)(plane + row * 64 + chunk * 16);
}

template <int ACT, int OUT>
__global__ __launch_bounds__(256, 2) void k_mgemm(
    const bf16_t* __restrict__ Ahi, const bf16_t* __restrict__ Alo,
    const bf16_t* __restrict__ Whi, const bf16_t* __restrict__ Wlo,
    const float* __restrict__ bias, float* __restrict__ C,
    bf16_t* __restrict__ Chi, bf16_t* __restrict__ Clo,
    int M, int N, int K) {
  __shared__ __align__(16) unsigned char smem[2][4][8192];
  const int t = threadIdx.x;
  const int lane = t & 63, wid = t >> 6;
  const int wr = wid >> 1, wc = wid & 1;
  const int rowBase = blockIdx.y * 128;
  const int colBase = blockIdx.x * 128;

  f32x4 acc[4][4] = {};

  const bf16_t* srcs[4] = {Ahi, Alo, Whi, Wlo};
  const int rb[4] = {rowBase, rowBase, colBase, colBase};

  auto stage = [&](int buf, int kt) {
    const int k0 = kt << 5;
#pragma unroll
    for (int p = 0; p < 4; ++p) {
#pragma unroll
      for (int issue = 0; issue < 2; ++issue) {
        const int orow = issue * 64 + wid * 16 + (lane >> 2);
        const int sc = (lane & 3) ^ ((orow >> 1) & 3);
        const bf16_t* g = srcs[p] + (size_t)(rb[p] + orow) * K + k0 + sc * 8;
        unsigned char* l = &smem[buf][p][issue * 4096 + wid * 1024];
        GLDS(g, l);
      }
    }
  };

  const int NK = K >> 5;
  stage(0, 0);
  for (int kt = 0; kt < NK; ++kt) {
    const int cur = kt & 1;
    __syncthreads();
    if (kt + 1 < NK) stage(cur ^ 1, kt + 1);
    const unsigned char* pa_hi = smem[cur][0];
    const unsigned char* pa_lo = smem[cur][1];
    const unsigned char* pw_hi = smem[cur][2];
    const unsigned char* pw_lo = smem[cur][3];
    bf16x8 ah[4], al[4], bh[4], bl[4];
#pragma unroll
    for (int m = 0; m < 4; ++m) {
      ah[m] = ldsread(pa_hi, wr * 4 + m, lane);
      al[m] = ldsread(pa_lo, wr * 4 + m, lane);
    }
#pragma unroll
    for (int n = 0; n < 4; ++n) {
      bh[n] = ldsread(pw_hi, wc * 4 + n, lane);
      bl[n] = ldsread(pw_lo, wc * 4 + n, lane);
    }
#pragma unroll
    for (int m = 0; m < 4; ++m)
#pragma unroll
      for (int n = 0; n < 4; ++n) {
        acc[m][n] = MFMA16(ah[m], bh[n], acc[m][n]);
        acc[m][n] = MFMA16(ah[m], bl[n], acc[m][n]);
        acc[m][n] = MFMA16(al[m], bh[n], acc[m][n]);
      }
  }

  const int r4 = lane >> 4;
  const int cn = lane & 15;
#pragma unroll
  for (int n = 0; n < 4; ++n) {
    const int col = colBase + wc * 64 + n * 16 + cn;
    const float bb = bias[col];
#pragma unroll
    for (int m = 0; m < 4; ++m) {
      const int row0 = rowBase + wr * 64 + m * 16 + r4 * 4;
#pragma unroll
      for (int r = 0; r < 4; ++r) {
        float x = acc[m][n][r] + bb;
        if (ACT == 1) x = fmaxf(x, 0.f);
        const size_t idx = (size_t)(row0 + r) * N + col;
        if (OUT == 0) {
          C[idx] = x;
        } else {
          const bf16_t hb = (bf16_t)x;
          Chi[idx] = hb;
          Clo[idx] = (bf16_t)(x - (float)hb);
        }
      }
    }
  }
}

// ---------------- MFMA attention: softmax(QK^T)V + residual + LN + row-sum --------
// o planes: [Mpad][768] split bf16 (q:0-127, k:128-255, v:256-767).
// 512 threads = 8 waves: wave w -> (rtile r = w&3, half h = w>>2).
__global__ __launch_bounds__(512, 4) void k_attn2(
    const bf16_t* __restrict__ ohi, const bf16_t* __restrict__ olo,
    const float* __restrict__ vf, const float* __restrict__ ln_g,
    const float* __restrict__ ln_b, bf16_t* __restrict__ vf2hi,
    bf16_t* __restrict__ vf2lo, float* __restrict__ vsum) {
  const int bt = blockIdx.x;
  const int t = threadIdx.x;
  const int lane = t & 63, w = t >> 6;
  const int g = lane >> 4, li = lane & 15;
  const int r = w & 3, h = w >> 2;
  const size_t rowbase = (size_t)bt * NSP;

  // LDS: phase1 qhi|qlo|khi|klo [64][136]bf16 (17408B each, 69632 total)
  //      phase2 P[2][64][72] (18432) + Vt[2][128][72] (36864) overlaid
  __shared__ __align__(16) unsigned char smem[69632];
  __shared__ float red[2][2][4][16];    // [max/sum][h][r][row]
  __shared__ float lnred[2][2][4][16];  // [sum/sumsq][h][r][row]
  __shared__ float vs_lds[4][512];

  // ---- stage q,k planes into padded LDS ----
  for (int u = t; u < 4096; u += 512) {
    const int pl = u >> 10, row = (u >> 4) & 63, c = u & 15;
    const bf16_t* src = (pl & 1) ? olo : ohi;
    bf16x8 val = *(const bf16x8*)(src + (rowbase + row) * 768 + (pl >> 1) * 128 + c * 8);
    *(bf16x8*)(smem + pl * 17408 + row * 272 + c * 16) = val;
  }
  __syncthreads();

  // ---- S = Q K^T (3-pass split) for rows r*16.., cols (2h+ct)*16.. ----
  f32x4 sacc[2] = {};
#pragma unroll
  for (int ks = 0; ks < 4; ++ks) {
    const bf16x8 ah = *(const bf16x8*)(smem + 0 * 17408 + (r * 16 + li) * 272 + ks * 64 + g * 16);
    const bf16x8 al = *(const bf16x8*)(smem + 1 * 17408 + (r * 16 + li) * 272 + ks * 64 + g * 16);
#pragma unroll
    for (int ct = 0; ct < 2; ++ct) {
      const int m = (h * 2 + ct) * 16 + li;
      const bf16x8 bh = *(const bf16x8*)(smem + 2 * 17408 + m * 272 + ks * 64 + g * 16);
      const bf16x8 bl = *(const bf16x8*)(smem + 3 * 17408 + m * 272 + ks * 64 + g * 16);
      sacc[ct] = MFMA16(ah, bh, sacc[ct]);
      sacc[ct] = MFMA16(ah, bl, sacc[ct]);
      sacc[ct] = MFMA16(al, bh, sacc[ct]);
    }
  }

  // ---- softmax (wave-parallel, cross-half via LDS) ----
  const int m0 = (h * 2 + 0) * 16 + li;
  const int m1 = (h * 2 + 1) * 16 + li;
  float e0[4], e1[4];
#pragma unroll
  for (int reg = 0; reg < 4; ++reg) {
    float s0 = (m0 < NSP) ? sacc[0][reg] : -1e30f;
    float s1 = (m1 < NSP) ? sacc[1][reg] : -1e30f;
    float mx = fmaxf(s0, s1);
#pragma unroll
    for (int off = 1; off < 16; off <<= 1) mx = fmaxf(mx, __shfl_xor(mx, off));
    if (li == 0) red[0][h][r][g * 4 + reg] = mx;
  }
  __syncthreads();
#pragma unroll
  for (int reg = 0; reg < 4; ++reg) {
    const float mx = fmaxf(red[0][0][r][g * 4 + reg], red[0][1][r][g * 4 + reg]);
    e0[reg] = (m0 < NSP) ? __expf(sacc[0][reg] - mx) : 0.f;
    e1[reg] = (m1 < NSP) ? __expf(sacc[1][reg] - mx) : 0.f;
    float su = e0[reg] + e1[reg];
#pragma unroll
    for (int off = 1; off < 16; off <<= 1) su += __shfl_xor(su, off);
    if (li == 0) red[1][h][r][g * 4 + reg] = su;
  }
  __syncthreads();
  // ---- write P hi/lo into LDS (overlays q region; q/k reads all done) ----
#pragma unroll
  for (int reg = 0; reg < 4; ++reg) {
    const float inv = 1.f / (red[1][0][r][g * 4 + reg] + red[1][1][r][g * 4 + reg]);
    const int nrow = r * 16 + g * 4 + reg;
#pragma unroll
    for (int ct = 0; ct < 2; ++ct) {
      const int m = (h * 2 + ct) * 16 + li;
      const float pv = (ct ? e1[reg] : e0[reg]) * inv;
      const bf16_t ph = (bf16_t)pv;
      *(bf16_t*)(smem + 0 * 9216 + nrow * 144 + m * 2) = ph;
      *(bf16_t*)(smem + 1 * 9216 + nrow * 144 + m * 2) = (bf16_t)(pv - (float)ph);
    }
  }
  __syncthreads();

  // ---- hoist P A-frags for this wave's rtile ----
  bf16x8 pa[2][2];
#pragma unroll
  for (int ks = 0; ks < 2; ++ks)
#pragma unroll
    for (int pl = 0; pl < 2; ++pl)
      pa[ks][pl] = *(const bf16x8*)(smem + pl * 9216 + (r * 16 + li) * 144 + ks * 64 + g * 16);

  // ---- PV over 4 d-chunks of 128; Vt[pl][128][72] at offset 18432 ----
  f32x4 oacc[4][4] = {};
  for (int c = 0; c < 4; ++c) {
    if (c > 0) __syncthreads();  // previous chunk's MFMAs done before overwrite
    for (int u = t; u < 1024; u += 512) {
      const int pl = u >> 9, mc = (u >> 6) & 7, dp = u & 63;
      const bf16_t* src = pl ? olo : ohi;
      const bf16_t* base = src + (rowbase + mc * 8) * 768 + 256 + c * 128 + dp * 2;
      bf16x8 r0, r1;
#pragma unroll
      for (int j = 0; j < 8; ++j) {
        const ushort2 vv = *(const ushort2*)(base + (size_t)j * 768);
        r0[j] = __builtin_bit_cast(bf16_t, (unsigned short)vv.x);
        r1[j] = __builtin_bit_cast(bf16_t, (unsigned short)vv.y);
      }
      unsigned char* vt = smem + 18432 + pl * 18432;
      *(bf16x8*)(vt + (dp * 2 + 0) * 144 + mc * 16) = r0;
      *(bf16x8*)(vt + (dp * 2 + 1) * 144 + mc * 16) = r1;
    }
    __syncthreads();
#pragma unroll
    for (int qd = 0; qd < 4; ++qd) {
      const int drow = (h * 4 + qd) * 16 + li;
#pragma unroll
      for (int ks = 0; ks < 2; ++ks) {
        const bf16x8 bh = *(const bf16x8*)(smem + 18432 + 0 * 18432 + drow * 144 + ks * 64 + g * 16);
        const bf16x8 bl = *(const bf16x8*)(smem + 18432 + 1 * 18432 + drow * 144 + ks * 64 + g * 16);
        oacc[c][qd] = MFMA16(pa[ks][0], bh, oacc[c][qd]);
        oacc[c][qd] = MFMA16(pa[ks][0], bl, oacc[c][qd]);
        oacc[c][qd] = MFMA16(pa[ks][1], bh, oacc[c][qd]);
      }
    }
  }

  // ---- residual + LN stats ----
#pragma unroll
  for (int c = 0; c < 4; ++c)
#pragma unroll
    for (int qd = 0; qd < 4; ++qd) {
      const int d = c * 128 + (h * 4 + qd) * 16 + li;
#pragma unroll
      for (int reg = 0; reg < 4; ++reg) {
        const int n = r * 16 + g * 4 + reg;
        if (n < NSP) oacc[c][qd][reg] += vf[(rowbase + n) * 512 + d];
      }
    }
  float mu[4], rs[4];
#pragma unroll
  for (int reg = 0; reg < 4; ++reg) {
    float s1 = 0.f, s2 = 0.f;
#pragma unroll
    for (int c = 0; c < 4; ++c)
#pragma unroll
      for (int qd = 0; qd < 4; ++qd) {
        const float x = oacc[c][qd][reg];
        s1 += x; s2 += x * x;
      }
#pragma unroll
    for (int off = 1; off < 16; off <<= 1) {
      s1 += __shfl_xor(s1, off);
      s2 += __shfl_xor(s2, off);
    }
    if (li == 0) { lnred[0][h][r][g * 4 + reg] = s1; lnred[1][h][r][g * 4 + reg] = s2; }
  }
  __syncthreads();
#pragma unroll
  for (int reg = 0; reg < 4; ++reg) {
    const float s1 = lnred[0][0][r][g * 4 + reg] + lnred[0][1][r][g * 4 + reg];
    const float s2 = lnred[1][0][r][g * 4 + reg] + lnred[1][1][r][g * 4 + reg];
    const float m_ = s1 * (1.f / VD);
    mu[reg] = m_;
    rs[reg] = rsqrtf(s2 * (1.f / VD) - m_ * m_ + 1e-5f);
  }

  // ---- normalize, store vf2 hi/lo, accumulate vsum ----
#pragma unroll
  for (int c = 0; c < 4; ++c)
#pragma unroll
    for (int qd = 0; qd < 4; ++qd) {
      const int d = c * 128 + (h * 4 + qd) * 16 + li;
      const float gd = ln_g[d], bd = ln_b[d];
      float vp = 0.f;
#pragma unroll
      for (int reg = 0; reg < 4; ++reg) {
        const int n = r * 16 + g * 4 + reg;
        const float y = (oacc[c][qd][reg] - mu[reg]) * rs[reg] * gd + bd;
        if (n < NSP) {
          const size_t idx = (rowbase + n) * 512 + d;
          const bf16_t hb = (bf16_t)y;
          vf2hi[idx] = hb;
          vf2lo[idx] = (bf16_t)(y - (float)hb);
          vp += y;
        }
      }
#pragma unroll
      for (int off = 16; off < 64; off <<= 1) vp += __shfl_xor(vp, off);
      if (g == 0) vs_lds[r][d] = vp;
    }
  __syncthreads();
  if (t < 512) {
    const float s = vs_lds[0][t] + vs_lds[1][t] + vs_lds[2][t] + vs_lds[3][t];
    vsum[(size_t)bt * 512 + t] = s;
  }
}

// ---------------- generic fp32 GEMM (small M) -------------------------------------
template <int ACT>  // 0 none, 1 relu, 2 sigmoid
__global__ __launch_bounds__(256) void k_gemm(const float* __restrict__ A,
                                              const float* __restrict__ W,
                                              const float* __restrict__ bias,
                                              float* __restrict__ C,
                                              int M, int N, int K, float alpha) {
  __shared__ __align__(16) float As[8][132];
  __shared__ __align__(16) float Ws[8][132];
  const int t = threadIdx.x;
  const int tx = t & 15, ty = t >> 4;
  const int rowBase = blockIdx.y * 128;
  const int colBase = blockIdx.x * 128;
  const int lrow = t >> 1, lq = t & 1;
  const float* Ap = A + (size_t)(rowBase + lrow) * K + lq * 4;
  const float* Wp = W + (size_t)(colBase + lrow) * K + lq * 4;
  float acc[8][8] = {};
  for (int k0 = 0; k0 < K; k0 += 8) {
    const float4 av = *(const float4*)(Ap + k0);
    const float4 wv = *(const float4*)(Wp + k0);
    __syncthreads();
    As[lq * 4 + 0][lrow] = av.x; As[lq * 4 + 1][lrow] = av.y;
    As[lq * 4 + 2][lrow] = av.z; As[lq * 4 + 3][lrow] = av.w;
    Ws[lq * 4 + 0][lrow] = wv.x; Ws[lq * 4 + 1][lrow] = wv.y;
    Ws[lq * 4 + 2][lrow] = wv.z; Ws[lq * 4 + 3][lrow] = wv.w;
    __syncthreads();
#pragma unroll
    for (int kk = 0; kk < 8; ++kk) {
      const float4 a0 = *(const float4*)&As[kk][ty * 8];
      const float4 a1 = *(const float4*)&As[kk][ty * 8 + 4];
      const float4 w0 = *(const float4*)&Ws[kk][tx * 8];
      const float4 w1 = *(const float4*)&Ws[kk][tx * 8 + 4];
      const float a_[8] = {a0.x, a0.y, a0.z, a0.w, a1.x, a1.y, a1.z, a1.w};
      const float w_[8] = {w0.x, w0.y, w0.z, w0.w, w1.x, w1.y, w1.z, w1.w};
#pragma unroll
      for (int i = 0; i < 8; ++i)
#pragma unroll
        for (int j = 0; j < 8; ++j)
          acc[i][j] = fmaf(a_[i], w_[j], acc[i][j]);
    }
  }
  const float4 b0 = *(const float4*)(bias + colBase + tx * 8);
  const float4 b1 = *(const float4*)(bias + colBase + tx * 8 + 4);
  const float bb[8] = {b0.x, b0.y, b0.z, b0.w, b1.x, b1.y, b1.z, b1.w};
#pragma unroll
  for (int i = 0; i < 8; ++i) {
    float* crow = C + (size_t)(rowBase + ty * 8 + i) * N + colBase + tx * 8;
    float o[8];
#pragma unroll
    for (int j = 0; j < 8; ++j) {
      float x = acc[i][j] * alpha + bb[j];
      if (ACT == 1) x = fmaxf(x, 0.f);
      if (ACT == 2) x = 1.f / (1.f + __expf(-x));
      o[j] = x;
    }
    *(float4*)(crow)     = make_float4(o[0], o[1], o[2], o[3]);
    *(float4*)(crow + 4) = make_float4(o[4], o[5], o[6], o[7]);
  }
}

// ------- shared: scores + softmax + weighted sum over spatial ---------------------
__global__ __launch_bounds__(256) void k_score_einsum(
    const float* __restrict__ Cm, const float* __restrict__ gate,
    const float* __restrict__ wvv, const float* __restrict__ bsc,
    const bf16_t* __restrict__ Vhi, const bf16_t* __restrict__ Vlo,
    const float* __restrict__ saf_in, float* __restrict__ outp) {
  const int bt = blockIdx.x, t = threadIdx.x;
  __shared__ float us[HD];
  __shared__ float sc[NSP];
  __shared__ float mp[NSP + 1];
  us[t] = gate[(size_t)bt * HD + t] * wvv[t];
  __syncthreads();
  const int lane = t & 63, w = t >> 6;
  const float bias0 = bsc[0];
  for (int n = w; n < NSP; n += 4) {
    const float* row = Cm + ((size_t)bt * NSP + n) * HD;
    float s = 0.f;
#pragma unroll
    for (int i = 0; i < HD / 64; ++i) s = fmaf(row[lane + 64 * i], us[lane + 64 * i], s);
    for (int off = 32; off; off >>= 1) s += __shfl_down(s, off);
    if (lane == 0) sc[n] = tanhf(s + bias0);
  }
  __syncthreads();
  if (t == 0) {
    float mx = -1e30f;
    for (int n = 0; n < NSP; ++n) mx = fmaxf(mx, sc[n]);
    float sum = 0.f;
    for (int n = 0; n < NSP; ++n) { float e = __expf(sc[n] - mx); mp[n] = e; sum += e; }
    float inv = 1.f / sum;
    for (int n = 0; n < NSP; ++n) mp[n] *= inv;
  }
  __syncthreads();
  for (int d = t; d < VD; d += 256) {
    const bf16_t* vh = Vhi + (size_t)bt * NSP * VD + d;
    const bf16_t* vl = Vlo + (size_t)bt * NSP * VD + d;
    float a = 0.f;
#pragma unroll
    for (int n = 0; n < NSP; ++n) {
      const float vv = (float)vh[(size_t)n * VD] + (float)vl[(size_t)n * VD];
      a = fmaf(mp[n], vv, a);
    }
    if (saf_in) {
      const float sg = 1.f / (1.f + __expf(-saf_in[(size_t)bt * VD + d]));
      a *= (1.f + BETA * sg);
    }
    outp[(size_t)bt * VD + d] = a;
  }
}

// ---------------- tmean[bt,d] = aq1[bt,d] * mean_n vq1[bt,n,d] --------------------
__global__ __launch_bounds__(512) void k_vq1mean(const float* __restrict__ vq1,
                                                 const float* __restrict__ aq1,
                                                 float* __restrict__ tmean) {
  const int bt = blockIdx.x, d = threadIdx.x;
  const float* p = vq1 + (size_t)bt * NSP * VD + d;
  float s = 0.f;
#pragma unroll
  for (int n = 0; n < NSP; ++n) s += p[(size_t)n * VD];
  tmean[(size_t)bt * VD + d] = s * (1.f / 49.f) * aq1[(size_t)bt * VD + d];
}

// ---------------- c_att = video * (ch+1) -> bf16 hi/lo planes ---------------------
__global__ __launch_bounds__(256) void k_catt(const float* __restrict__ video,
                                              const float* __restrict__ ch,
                                              bf16_t* __restrict__ hi,
                                              bf16_t* __restrict__ lo) {
  const size_t i8 = (size_t)blockIdx.x * 256 + threadIdx.x;
  const size_t i = i8 * 8;
  const size_t bt = i / ((size_t)NSP * VD);
  const int d = (int)(i & (VD - 1));
  const float4 v0 = ((const float4*)(video + i))[0];
  const float4 v1 = ((const float4*)(video + i))[1];
  const float4 c0 = *(const float4*)(ch + bt * VD + d);
  const float4 c1 = *(const float4*)(ch + bt * VD + d + 4);
  const float xs[8] = {v0.x * (c0.x + 1.f), v0.y * (c0.y + 1.f),
                       v0.z * (c0.z + 1.f), v0.w * (c0.w + 1.f),
                       v1.x * (c1.x + 1.f), v1.y * (c1.y + 1.f),
                       v1.z * (c1.z + 1.f), v1.w * (c1.w + 1.f)};
  bf16x8 h, l;
#pragma unroll
  for (int j = 0; j < 8; ++j) {
    const bf16_t hb = (bf16_t)xs[j];
    h[j] = hb;
    l[j] = (bf16_t)(xs[j] - (float)hb);
  }
  ((bf16x8*)hi)[i8] = h;
  ((bf16x8*)lo)[i8] = l;
}

extern "C" void kernel_launch(void* const* d_in, const int* in_sizes, int n_in,
                              void* d_out, int out_size, void* d_ws, size_t ws_size,
                              hipStream_t stream) {
  const float* video  = (const float*)d_in[0];
  const float* audio  = (const float*)d_in[1];
  const float* wq     = (const float*)d_in[2];  const float* bq     = (const float*)d_in[3];
  const float* wk     = (const float*)d_in[4];  const float* bk     = (const float*)d_in[5];
  const float* wv     = (const float*)d_in[6];  const float* bv     = (const float*)d_in[7];
  const float* ln_g   = (const float*)d_in[8];  const float* ln_b   = (const float*)d_in[9];
  const float* w_ave  = (const float*)d_in[10]; const float* b_ave  = (const float*)d_in[11];
  const float* w_v3   = (const float*)d_in[12]; const float* b_v3   = (const float*)d_in[13];
  const float* w_avatt= (const float*)d_in[14]; const float* b_avatt= (const float*)d_in[15];
  const float* w_a1   = (const float*)d_in[16]; const float* b_a1   = (const float*)d_in[17];
  const float* w_v1   = (const float*)d_in[18]; const float* b_v1   = (const float*)d_in[19];
  const float* w_bn   = (const float*)d_in[20]; const float* b_bn   = (const float*)d_in[21];
  const float* w_ca   = (const float*)d_in[22]; const float* b_ca   = (const float*)d_in[23];
  const float* w_v2   = (const float*)d_in[24]; const float* b_v2   = (const float*)d_in[25];
  const float* w_a2   = (const float*)d_in[26]; const float* b_a2   = (const float*)d_in[27];
  const float* w_sa   = (const float*)d_in[28]; const float* b_sa   = (const float*)d_in[29];

  float* out = (float*)d_out;
  float* out_audio = out + (size_t)BT * VD;

  const size_t M = (size_t)BT * NSP;      // 125440
  const size_t Mpad = M + 64;             // slack rows for padded-64 bt reads

  unsigned char* p = (unsigned char*)d_ws;
  auto carve = [&](size_t bytes) { unsigned char* r = p; p += (bytes + 255) & ~(size_t)255; return r; };
  bf16_t* vhi  = (bf16_t*)carve(M * VD * 2);            // video planes -> reused as vf2 planes
  bf16_t* vlo  = (bf16_t*)carve(M * VD * 2);
  bf16_t* wch  = (bf16_t*)carve((size_t)768 * VD * 2);  // [wq|wk|wv] hi
  bf16_t* wcl  = (bf16_t*)carve((size_t)768 * VD * 2);
  bf16_t* w3h  = (bf16_t*)carve((size_t)HD * VD * 2);
  bf16_t* w3l  = (bf16_t*)carve((size_t)HD * VD * 2);
  bf16_t* w1h  = (bf16_t*)carve((size_t)VD * VD * 2);
  bf16_t* w1l  = (bf16_t*)carve((size_t)VD * VD * 2);
  bf16_t* w2h  = (bf16_t*)carve((size_t)HD * VD * 2);
  bf16_t* w2l  = (bf16_t*)carve((size_t)HD * VD * 2);
  float*  bcat = (float*)carve(768 * 4);
  bf16_t* o_hi = (bf16_t*)carve(Mpad * 768 * 2 * 2);    // o_hi + o_lo contiguous
  bf16_t* o_lo = o_hi + Mpad * 768;
  float* vsum  = (float*)carve((size_t)BT * VD * 4);
  float* vavg  = (float*)carve((size_t)BT * HD * 4);
  float* aq1   = (float*)carve((size_t)BT * VD * 4);
  float* aq2   = (float*)carve((size_t)BT * HD * 4);
  float* tmean = (float*)carve((size_t)BT * VD * 4);
  float* avq   = (float*)carve((size_t)BT * HD * 4);
  float* saf   = (float*)carve((size_t)BT * VD * 4);
  float* ch    = (float*)carve((size_t)BT * VD * 4);
  // lifetime-disjoint overlays inside the dead o region:
  float*  vq1    = (float*)o_hi;                        // [M,VD] f32 (257MB <= 386MB)
  bf16_t* catthi = o_hi;                                // [M,VD] bf16
  bf16_t* cattlo = o_hi + M * VD;
  float*  C12    = (float*)(o_hi + 2 * M * VD);         // [M,HD] f32 after catt planes
  bf16_t *vf2hi = vhi, *vf2lo = vlo;

  const dim3 blk(256);

  k_audio<<<BT, AD, 0, stream>>>(audio, out_audio);

  // split inputs/weights into bf16 hi/lo planes
  k_split<<<(int)(M * VD / 8 / 256), blk, 0, stream>>>(video, vhi, vlo);
  k_split<<<QD * VD / 8 / 256, blk, 0, stream>>>(wq, wch, wcl);
  k_split<<<QD * VD / 8 / 256, blk, 0, stream>>>(wk, wch + (size_t)QD * VD, wcl + (size_t)QD * VD);
  k_split<<<VD * VD / 8 / 256, blk, 0, stream>>>(wv, wch + (size_t)2 * QD * VD, wcl + (size_t)2 * QD * VD);
  k_split<<<HD * VD / 8 / 256, blk, 0, stream>>>(w_v3, w3h, w3l);
  k_split<<<VD * VD / 8 / 256, blk, 0, stream>>>(w_v1, w1h, w1l);
  k_split<<<HD * VD / 8 / 256, blk, 0, stream>>>(w_v2, w2h, w2l);
  k_bcat<<<3, blk, 0, stream>>>(bq, bk, bv, bcat);

  // fused QKV projection -> split-bf16 o planes
  k_mgemm<0, 1><<<dim3(6, M / 128), blk, 0, stream>>>(vhi, vlo, wch, wcl, bcat,
                                                      nullptr, o_hi, o_lo, M, 768, VD);
  // MFMA attention + LN + row-sum
  k_attn2<<<BT, 512, 0, stream>>>(o_hi, o_lo, video, ln_g, ln_b, vf2hi, vf2lo, vsum);

  // small fp32 GEMMs
  k_gemm<1><<<dim3(HD / 128, BT / 128), blk, 0, stream>>>(vsum, w_ave, b_ave, vavg, BT, HD, VD, 1.f / 49.f);
  k_gemm<1><<<dim3(VD / 128, BT / 128), blk, 0, stream>>>(out_audio, w_a1, b_a1, aq1, BT, VD, AD, 1.f);
  k_gemm<1><<<dim3(HD / 128, BT / 128), blk, 0, stream>>>(out_audio, w_a2, b_a2, aq2, BT, HD, AD, 1.f);

  // self spatial attention branch
  k_mgemm<1, 0><<<dim3(HD / 128, M / 128), blk, 0, stream>>>(vf2hi, vf2lo, w3h, w3l, b_v3,
                                                             C12, nullptr, nullptr, M, HD, VD);
  k_score_einsum<<<BT, 256, 0, stream>>>(C12, vavg, w_avatt, b_avatt, vf2hi, vf2lo, nullptr, saf);

  // audio-guided channel attention
  k_mgemm<1, 0><<<dim3(VD / 128, M / 128), blk, 0, stream>>>(vf2hi, vf2lo, w1h, w1l, b_v1,
                                                             vq1, nullptr, nullptr, M, VD, VD);
  k_vq1mean<<<BT, VD, 0, stream>>>(vq1, aq1, tmean);
  k_gemm<1><<<dim3(HD / 128, BT / 128), blk, 0, stream>>>(tmean, w_bn, b_bn, avq, BT, HD, VD, 1.f);
  k_gemm<2><<<dim3(VD / 128, BT / 128), blk, 0, stream>>>(avq, w_ca, b_ca, ch, BT, VD, HD, 1.f);
  k_catt<<<(int)(M * VD / 8 / 256), blk, 0, stream>>>(video, ch, catthi, cattlo);

  // audio-guided spatial attention + final combine
  k_mgemm<1, 0><<<dim3(HD / 128, M / 128), blk, 0, stream>>>(catthi, cattlo, w2h, w2l, b_v2,
                                                             C12, nullptr, nullptr, M, HD, VD);
  k_score_einsum<<<BT, 256, 0, stream>>>(C12, aq2, w_sa, b_sa, catthi, cattlo, saf, out);
}